// Round 2
// baseline (3149.961 us; speedup 1.0000x reference)
//
#include <hip/hip_runtime.h>

// ---------- types ----------
using bf16x8 = __attribute__((ext_vector_type(8))) __bf16;
using f32x4  = __attribute__((ext_vector_type(4))) float;

__device__ __forceinline__ f32x4 mfma16(bf16x8 a, bf16x8 b, f32x4 c) {
    return __builtin_amdgcn_mfma_f32_16x16x32_bf16(a, b, c, 0, 0, 0);
}

__device__ __forceinline__ bf16x8 cvt8v(float4 u, float4 v) {
    bf16x8 r;
    r[0] = (__bf16)u.x; r[1] = (__bf16)u.y; r[2] = (__bf16)u.z; r[3] = (__bf16)u.w;
    r[4] = (__bf16)v.x; r[5] = (__bf16)v.y; r[6] = (__bf16)v.z; r[7] = (__bf16)v.w;
    return r;
}

// ---------- constants ----------
#define HID   1024
#define B3    3072
#define NB    64      // batch
#define TENC  40
#define TDEC  27
#define VOC   32000

// ---------- zero init of h states (first ping-pong buffer each) ----------
__global__ __launch_bounds__(256) void zero_h(__bf16* __restrict__ h1, __bf16* __restrict__ h2) {
    int i = blockIdx.x * 256 + threadIdx.x;   // 65536 threads
    h1[i] = (__bf16)0.f;
    h2[i] = (__bf16)0.f;
}

// ---------- f32 -> bf16 weight conversion, gathering first `1<<logc` cols of rows with stride ld ----------
__global__ __launch_bounds__(256) void cvt_w(const float* __restrict__ src, int ld, int logc,
                                             __bf16* __restrict__ dst, int n) {
    int i = blockIdx.x * 256 + threadIdx.x;
    if (i < n) {
        int row = i >> logc, col = i & ((1 << logc) - 1);
        dst[i] = (__bf16)src[(size_t)row * ld + col];
    }
}

// ---------- word gather: words[t*64+b][:] = bf16(emb[tgt[b][t]][:]) ----------
__global__ __launch_bounds__(64) void gather_words(const float* __restrict__ emb,
                                                   const int* __restrict__ tgt,
                                                   __bf16* __restrict__ words) {
    int row = blockIdx.x;            // 0..1727  = t*64 + b
    int b = row & 63, t = row >> 6;
    int idx = tgt[b * 28 + t];
    const float* src = emb + (size_t)idx * 512 + threadIdx.x * 8;
    float4 u = *(const float4*)src;
    float4 v = *(const float4*)(src + 4);
    *(bf16x8*)(words + (size_t)row * 512 + threadIdx.x * 8) = cvt8v(u, v);
}

// ---------- tiled GEMM: C = A(MxK) @ B(NxK)^T + bias ----------
// A dtype templated (float or __bf16); B is float; MFMA in bf16.
// out row remap: orow = (m % mdiv)*ms1 + (m / mdiv)*ms2
template <typename TA, bool OUTBF>
__global__ __launch_bounds__(256) void gemm_bt(
    const TA* __restrict__ A, int lda,
    const float* __restrict__ Bw, int ldb,
    const float* __restrict__ bias,
    void* __restrict__ Cout, int ldc,
    int K, int mdiv, int ms1, int ms2)
{
    __shared__ __align__(16) __bf16 As[64][40];
    __shared__ __align__(16) __bf16 Bs[64][40];
    const int tid  = threadIdx.x;
    const int m0   = blockIdx.x * 64;
    const int n0   = blockIdx.y * 64;
    const int srow = tid >> 2;
    const int sseg = (tid & 3) * 8;
    const TA*    ga = A  + (size_t)(m0 + srow) * lda + sseg;
    const float* gb = Bw + (size_t)(n0 + srow) * ldb + sseg;
    const int lane  = tid & 63, wave = tid >> 6;
    const int wm    = (wave >> 1) * 32, wn = (wave & 1) * 32;
    const int row15 = lane & 15, quad = lane >> 4;

    f32x4 acc[2][2] = {};
    for (int k = 0; k < K; k += 32) {
        __syncthreads();
        if constexpr (__is_same(TA, float)) {
            float4 u = *(const float4*)(ga + k);
            float4 v = *(const float4*)(ga + k + 4);
            *(bf16x8*)&As[srow][sseg] = cvt8v(u, v);
        } else {
            *(bf16x8*)&As[srow][sseg] = *(const bf16x8*)(ga + k);
        }
        {
            float4 u = *(const float4*)(gb + k);
            float4 v = *(const float4*)(gb + k + 4);
            *(bf16x8*)&Bs[srow][sseg] = cvt8v(u, v);
        }
        __syncthreads();
        bf16x8 a0 = *(const bf16x8*)&As[wm + row15][quad * 8];
        bf16x8 a1 = *(const bf16x8*)&As[wm + 16 + row15][quad * 8];
        bf16x8 b0 = *(const bf16x8*)&Bs[wn + row15][quad * 8];
        bf16x8 b1 = *(const bf16x8*)&Bs[wn + 16 + row15][quad * 8];
        acc[0][0] = mfma16(a0, b0, acc[0][0]);
        acc[0][1] = mfma16(a0, b1, acc[0][1]);
        acc[1][0] = mfma16(a1, b0, acc[1][0]);
        acc[1][1] = mfma16(a1, b1, acc[1][1]);
    }
    #pragma unroll
    for (int mt = 0; mt < 2; ++mt)
        #pragma unroll
        for (int nt = 0; nt < 2; ++nt)
            #pragma unroll
            for (int i = 0; i < 4; ++i) {
                int m = m0 + wm + mt * 16 + quad * 4 + i;
                int n = n0 + wn + nt * 16 + row15;
                int orow = (m % mdiv) * ms1 + (m / mdiv) * ms2;
                float v = acc[mt][nt][i] + bias[n];
                if constexpr (OUTBF)
                    ((__bf16*)Cout)[(size_t)orow * ldc + n] = (__bf16)v;
                else
                    ((float*)Cout)[(size_t)orow * ldc + n] = v;
            }
}

// ---------- fused GRU step (one wave per 16x16 tile of h_new) ----------
// gh = h_prev @ Whh^T + bhh;  gi = [HAS_IH: hx @ Wih^T] + bih + pre
// r=sig(ir+hr) z=sig(iz+hz) n=tanh(in+r*hn) h=(1-z)n+z*h_prev
// Whh/Wih are pre-converted bf16, ld = HID.
template <bool HAS_IH>
__global__ __launch_bounds__(64) void gru_step(
    const __bf16* __restrict__ hprev,
    const __bf16* __restrict__ Whh, const float* __restrict__ bhh,
    const __bf16* __restrict__ hx,  const __bf16* __restrict__ Wih,
    const __bf16* __restrict__ pre, const float* __restrict__ bih,
    __bf16* __restrict__ hout, __bf16* __restrict__ hout2)
{
    const int lane  = threadIdx.x;
    const int mtile = blockIdx.x & 3;     // 4 x 16 batch rows
    const int ntile = blockIdx.x >> 2;    // 64 x 16 hidden cols
    const int row15 = lane & 15, quad = lane >> 4;
    const int koff  = quad * 8;

    const int arow = mtile * 16 + row15;
    const __bf16* ap = hprev + (size_t)arow * HID + koff;
    const __bf16* xp = HAS_IH ? hx + (size_t)arow * HID + koff : nullptr;

    const int brow = ntile * 16 + row15;
    const __bf16* w0 = Whh + (size_t)(brow)          * HID + koff;
    const __bf16* w1 = Whh + (size_t)(brow + HID)    * HID + koff;
    const __bf16* w2 = Whh + (size_t)(brow + 2*HID)  * HID + koff;
    const __bf16 *u0 = nullptr, *u1 = nullptr, *u2 = nullptr;
    if (HAS_IH) {
        u0 = Wih + (size_t)(brow)         * HID + koff;
        u1 = Wih + (size_t)(brow + HID)   * HID + koff;
        u2 = Wih + (size_t)(brow + 2*HID) * HID + koff;
    }

    f32x4 ah0 = {}, ah1 = {}, ah2 = {};
    f32x4 ai0 = {}, ai1 = {}, ai2 = {};
    #pragma unroll 4
    for (int k = 0; k < HID; k += 32) {
        bf16x8 a = *(const bf16x8*)(ap + k);
        ah0 = mfma16(a, *(const bf16x8*)(w0 + k), ah0);
        ah1 = mfma16(a, *(const bf16x8*)(w1 + k), ah1);
        ah2 = mfma16(a, *(const bf16x8*)(w2 + k), ah2);
        if (HAS_IH) {
            bf16x8 ax = *(const bf16x8*)(xp + k);
            ai0 = mfma16(ax, *(const bf16x8*)(u0 + k), ai0);
            ai1 = mfma16(ax, *(const bf16x8*)(u1 + k), ai1);
            ai2 = mfma16(ax, *(const bf16x8*)(u2 + k), ai2);
        }
    }

    const int j = ntile * 16 + row15;
    const float bh0 = bhh[j], bh1 = bhh[HID + j], bh2 = bhh[2*HID + j];
    float bi0 = 0.f, bi1 = 0.f, bi2 = 0.f;
    if (bih) { bi0 = bih[j]; bi1 = bih[HID + j]; bi2 = bih[2*HID + j]; }

    #pragma unroll
    for (int i = 0; i < 4; ++i) {
        int m = mtile * 16 + quad * 4 + i;
        float gir = ai0[i] + bi0, giz = ai1[i] + bi1, gin = ai2[i] + bi2;
        if (pre) {
            const __bf16* pp = pre + (size_t)m * B3 + j;
            gir += (float)pp[0];
            giz += (float)pp[HID];
            gin += (float)pp[2*HID];
        }
        float ghr = ah0[i] + bh0, ghz = ah1[i] + bh1, ghn = ah2[i] + bh2;
        float r = 1.f / (1.f + expf(-(gir + ghr)));
        float z = 1.f / (1.f + expf(-(giz + ghz)));
        float n = tanhf(gin + r * ghn);
        float ho = (float)hprev[(size_t)m * HID + j];
        float hv = (1.f - z) * n + z * ho;
        hout[(size_t)m * HID + j] = (__bf16)hv;
        if (hout2) hout2[(size_t)m * HID + j] = (__bf16)hv;
    }
}

// ---------- in-place row log-softmax over 32000 f32 cols ----------
__global__ __launch_bounds__(256) void logsoftmax_rows(float* __restrict__ out) {
    const int r = blockIdx.x;
    float* p = out + (size_t)r * VOC;
    const int tid = threadIdx.x;
    const int lane = tid & 63, wid = tid >> 6;
    __shared__ float red[4];
    __shared__ float bc[2];

    float mx = -3.0e38f;
    for (int c = tid; c < VOC / 4; c += 256) {
        float4 v = ((const float4*)p)[c];
        mx = fmaxf(mx, fmaxf(fmaxf(v.x, v.y), fmaxf(v.z, v.w)));
    }
    #pragma unroll
    for (int o = 32; o > 0; o >>= 1) mx = fmaxf(mx, __shfl_down(mx, o));
    if (lane == 0) red[wid] = mx;
    __syncthreads();
    if (tid == 0) bc[0] = fmaxf(fmaxf(red[0], red[1]), fmaxf(red[2], red[3]));
    __syncthreads();
    mx = bc[0];

    float s = 0.f;
    for (int c = tid; c < VOC / 4; c += 256) {
        float4 v = ((const float4*)p)[c];
        s += expf(v.x - mx) + expf(v.y - mx) + expf(v.z - mx) + expf(v.w - mx);
    }
    #pragma unroll
    for (int o = 32; o > 0; o >>= 1) s += __shfl_down(s, o);
    if (lane == 0) red[wid] = s;
    __syncthreads();
    if (tid == 0) bc[1] = mx + logf(red[0] + red[1] + red[2] + red[3]);
    __syncthreads();
    const float C = bc[1];

    for (int c = tid; c < VOC / 4; c += 256) {
        float4 v = ((const float4*)p)[c];
        v.x -= C; v.y -= C; v.z -= C; v.w -= C;
        ((float4*)p)[c] = v;
    }
}

// ---------- launch ----------
extern "C" void kernel_launch(void* const* d_in, const int* in_sizes, int n_in,
                              void* d_out, int out_size, void* d_ws, size_t ws_size,
                              hipStream_t stream) {
    const float* vid  = (const float*)d_in[0];
    const int*   tgt  = (const int*)d_in[1];
    const float* emb  = (const float*)d_in[2];
    const float* Wih1 = (const float*)d_in[3];
    const float* Whh1 = (const float*)d_in[4];
    const float* bih1 = (const float*)d_in[5];
    const float* bhh1 = (const float*)d_in[6];
    const float* Wih2 = (const float*)d_in[7];
    const float* Whh2 = (const float*)d_in[8];
    const float* bih2 = (const float*)d_in[9];
    const float* bhh2 = (const float*)d_in[10];
    const float* Wout = (const float*)d_in[11];
    const float* bout = (const float*)d_in[12];
    float* out = (float*)d_out;

    char* w = (char*)d_ws;
    __bf16* h1b   = (__bf16*)w; w += (size_t)2 * NB * HID * 2;            // 2 x 64x1024
    __bf16* h2b   = (__bf16*)w; w += (size_t)2 * NB * HID * 2;
    __bf16* h2all = (__bf16*)w; w += (size_t)TDEC * NB * HID * 2;         // 1728x1024
    __bf16* gi1   = (__bf16*)w; w += (size_t)TENC * NB * B3 * 2;          // 2560x3072
    __bf16* wproj = (__bf16*)w; w += (size_t)TDEC * NB * B3 * 2;          // 1728x3072
    __bf16* words = (__bf16*)w; w += (size_t)TDEC * NB * 512 * 2;         // 1728x512
    __bf16* Whh1c = (__bf16*)w; w += (size_t)B3 * HID * 2;                // 3072x1024 bf16
    __bf16* Whh2c = (__bf16*)w; w += (size_t)B3 * HID * 2;
    __bf16* Wih2c = (__bf16*)w; w += (size_t)B3 * HID * 2;                // Wih2[:, :1024]

    const int HB = NB * HID;   // 65536
    const int NW = B3 * HID;   // 3.15M

    zero_h<<<256, 256, 0, stream>>>(h1b, h2b);
    cvt_w<<<(NW + 255) / 256, 256, 0, stream>>>(Whh1, 1024, 10, Whh1c, NW);
    cvt_w<<<(NW + 255) / 256, 256, 0, stream>>>(Whh2, 1024, 10, Whh2c, NW);
    cvt_w<<<(NW + 255) / 256, 256, 0, stream>>>(Wih2, 1536, 10, Wih2c, NW);

    // gi1[t*64+b][:] = vid[b][t][:] @ Wih1^T + bih1   (A row m=b*40+t -> orow=(m%40)*64+m/40)
    gemm_bt<float, true><<<dim3(TENC, 48), 256, 0, stream>>>(
        vid, 2048, Wih1, 2048, bih1, gi1, B3, 2048, TENC, 64, 1);

    gather_words<<<TDEC * NB, 64, 0, stream>>>(emb, tgt, words);

    // wproj[t*64+b][:] = words row @ Wih2[:,1024:]^T + bih2   (direct rows)
    gemm_bt<__bf16, true><<<dim3(TDEC, 48), 256, 0, stream>>>(
        words, 512, Wih2 + 1024, 1536, bih2, wproj, B3, 512, 1 << 30, 1, 0);

    int c1 = 0, c2 = 0;
    for (int t = 0; t < TENC; ++t) {
        gru_step<false><<<256, 64, 0, stream>>>(h1b + c1 * HB, Whh1c, bhh1,
                                                nullptr, nullptr,
                                                gi1 + (size_t)t * NB * B3, nullptr,
                                                h1b + (c1 ^ 1) * HB, nullptr);
        c1 ^= 1;
        gru_step<true><<<256, 64, 0, stream>>>(h2b + c2 * HB, Whh2c, bhh2,
                                               h1b + c1 * HB, Wih2c,
                                               nullptr, bih2,
                                               h2b + (c2 ^ 1) * HB, nullptr);
        c2 ^= 1;
    }
    for (int t = 0; t < TDEC; ++t) {
        gru_step<false><<<256, 64, 0, stream>>>(h1b + c1 * HB, Whh1c, bhh1,
                                                nullptr, nullptr,
                                                nullptr, bih1,
                                                h1b + (c1 ^ 1) * HB, nullptr);
        c1 ^= 1;
        gru_step<true><<<256, 64, 0, stream>>>(h2b + c2 * HB, Whh2c, bhh2,
                                               h1b + c1 * HB, Wih2c,
                                               wproj + (size_t)t * NB * B3, nullptr,
                                               h2b + (c2 ^ 1) * HB, h2all + (size_t)t * HB);
        c2 ^= 1;
    }

    // logits: h2all(1728x1024) @ Wout^T + bout -> out rows b*27+t   (m=t*64+b)
    gemm_bt<__bf16, false><<<dim3(TDEC, VOC / 64), 256, 0, stream>>>(
        h2all, 1024, Wout, 1024, bout, out, VOC, 1024, 64, TDEC, 1);

    logsoftmax_rows<<<TDEC * NB, 256, 0, stream>>>(out);
}